// Round 3
// baseline (666.651 us; speedup 1.0000x reference)
//
#include <hip/hip_runtime.h>
#include <hip/hip_bf16.h>
#include <math.h>

#define NNODES 100000
#define NEDGES 400000
#define INDIM  128
#define HDIM   256
#define MAXDEG 32

// GEMM tile: BM=64 x BN=256 (full output width -> A read exactly once)
#define BM 64
#define BN 256
#define BK 64
#define MTILES 1563           // ceil(NNODES/64)

typedef __attribute__((ext_vector_type(8))) short short8;
typedef __attribute__((ext_vector_type(8))) unsigned short ushort8v;
typedef __attribute__((ext_vector_type(4))) float f32x4;

__device__ __forceinline__ float bf2f(unsigned short u) {
    union { unsigned int i; float f; } v; v.i = ((unsigned int)u) << 16; return v.f;
}
__device__ __forceinline__ unsigned short f2bf(float f) {
    union { float f; unsigned int i; } v; v.f = f;
    unsigned int r = v.i + 0x7fffu + ((v.i >> 16) & 1u);   // RNE
    return (unsigned short)(r >> 16);
}

// ---------------- fused prep: convert_x + 3x convert_w + build_elist --------
#define XB_BLOCKS 12500                     // NNODES*INDIM/4 / 256
#define W0_BLOCKS 256                       // HDIM*2*INDIM / 256
#define W1_BLOCKS 512                       // HDIM*2*HDIM / 256
#define EL_BLOCKS 1563                      // ceil(NEDGES/256)
#define PREP_BLOCKS (XB_BLOCKS + W0_BLOCKS + 2 * W1_BLOCKS + EL_BLOCKS)

__global__ void prep_kernel(const float* __restrict__ x, unsigned short* __restrict__ xb,
                            const float* __restrict__ Wr0, const float* __restrict__ Ws0,
                            unsigned short* __restrict__ B0,
                            const float* __restrict__ Wr1, const float* __restrict__ Ws1,
                            unsigned short* __restrict__ B1,
                            const float* __restrict__ Wr2, const float* __restrict__ Ws2,
                            unsigned short* __restrict__ B2,
                            const int* __restrict__ ei, int* __restrict__ cnt,
                            int* __restrict__ elist) {
    int b = blockIdx.x;
    if (b < XB_BLOCKS) {
        int i = b * 256 + threadIdx.x;
        float4 v = ((const float4*)x)[i];
        ushort4 o; o.x = f2bf(v.x); o.y = f2bf(v.y); o.z = f2bf(v.z); o.w = f2bf(v.w);
        ((ushort4*)xb)[i] = o;
        return;
    }
    b -= XB_BLOCKS;
    if (b < W0_BLOCKS + 2 * W1_BLOCKS) {
        const float *Wr, *Ws; unsigned short* B; int K;
        if (b < W0_BLOCKS)               { Wr = Wr0; Ws = Ws0; B = B0; K = INDIM; }
        else if (b < W0_BLOCKS + W1_BLOCKS) { Wr = Wr1; Ws = Ws1; B = B1; K = HDIM; b -= W0_BLOCKS; }
        else                              { Wr = Wr2; Ws = Ws2; B = B2; K = HDIM; b -= W0_BLOCKS + W1_BLOCKS; }
        int idx = b * 256 + threadIdx.x;
        int n = idx / (2 * K);
        int k = idx - n * 2 * K;
        float v = (k < K) ? Wr[n * K + k] : Ws[n * K + (k - K)];
        B[idx] = f2bf(v);
        return;
    }
    b -= W0_BLOCKS + 2 * W1_BLOCKS;
    int e = b * 256 + threadIdx.x;
    if (e < NEDGES) {
        int d = ei[NEDGES + e];            // dst
        int s = ei[e];                     // src
        int pos = atomicAdd(&cnt[d], 1);
        if (pos < MAXDEG) elist[d * MAXDEG + pos] = s;
    }
}

// ---------------- fused gather + dual-GEMM + bias + relu --------------------
// Block covers rows m0..m0+63 x ALL 256 output cols.
// Phase 1: gather 64 nodes' neighbor sums into swizzled LDS tile (Agg, only
//          LDS use -> 32KB -> 3-4 blocks/CU).
// Phase 2: Ws-half GEMM (self rows x B[:,K:2K]) with A/B fragments loaded
//          DIRECTLY from global (L2/L3-resident) -- no LDS, no barriers.
// Phase 3: one __syncthreads, then Wr-half GEMM reading A-frags from the
//          resident Agg tile (LDS) and B-frags direct from global.
// K-loops are barrier-free and fully unrolled (K is a template param).
template<int MODE, int K>
__global__ __launch_bounds__(256, 3)
void fused_gconv(const unsigned short* __restrict__ h,
                 const int* __restrict__ cnt, const int* __restrict__ elist,
                 const unsigned short* __restrict__ B, const float* __restrict__ bias,
                 unsigned short* __restrict__ hout,
                 float* __restrict__ xs, float* __restrict__ x1o, float* __restrict__ x2o,
                 const float* __restrict__ Wsp1, const float* __restrict__ Wsp2,
                 float* __restrict__ spart) {
    __shared__ __align__(16) unsigned char smem[32768];
    unsigned short* Agg = (unsigned short*)smem;              // 64 x K bf16, swizzled

    const int tid  = threadIdx.x;
    const int lane = tid & 63;
    const int wv   = tid >> 6;            // wave: rows wv*16.. in gather, cols wv*64.. in GEMM
    const int m0   = blockIdx.x * BM;
    constexpr int Ktot = 2 * K;

    // ---- issue cnt + elist prefetch (to VGPRs) first ----
    const int lane31 = lane & 31;
    const int hw     = lane >> 5;
    int pn = m0 + wv * 16 + (lane >> 2);
    if (pn >= NNODES) pn = NNODES - 1;
    const int4 elv = ((const int4*)(elist + (size_t)pn * MAXDEG))[lane & 3];  // covers deg<=16
    int cnode = m0 + wv * 16 + (lane & 15);
    if (cnode >= NNODES) cnode = NNODES - 1;
    const int cv = cnt[cnode];

    // ---- gather phase: 2 nodes per wave per round, 8 rounds ----
    if constexpr (K == 256) {
        for (int rd = 0; rd < 8; rd++) {
            const int iw = rd * 2 + hw;                 // in-block-wave node 0..15
            int cA = __shfl(cv, rd * 2);                // convergent: all shfl valid
            int cB = __shfl(cv, rd * 2 + 1);
            if (cA > MAXDEG) cA = MAXDEG;
            if (cB > MAXDEG) cB = MAXDEG;
            const int c    = hw ? cB : cA;
            const int cmax = cA > cB ? cA : cB;         // wave-uniform trip count
            int node = m0 + wv * 16 + iw;
            if (node >= NNODES) node = NNODES - 1;
            float a[8];
            #pragma unroll
            for (int i = 0; i < 8; i++) a[i] = 0.f;
            for (int j0 = 0; j0 < cmax; j0 += 4) {
                int4 e;
                if (j0 < 16) {
                    int src = iw * 4 + (j0 >> 2);
                    e.x = __shfl(elv.x, src); e.y = __shfl(elv.y, src);
                    e.z = __shfl(elv.z, src); e.w = __shfl(elv.w, src);
                } else {
                    e = ((const int4*)(elist + (size_t)node * MAXDEG))[j0 >> 2];
                }
                int rem = c - j0;
                ushort8v v0 = {0,0,0,0,0,0,0,0}, v1 = v0, v2 = v0, v3 = v0;
                if (rem > 0) v0 = ((const ushort8v*)(h + (size_t)e.x * 256))[lane31];
                if (rem > 1) v1 = ((const ushort8v*)(h + (size_t)e.y * 256))[lane31];
                if (rem > 2) v2 = ((const ushort8v*)(h + (size_t)e.z * 256))[lane31];
                if (rem > 3) v3 = ((const ushort8v*)(h + (size_t)e.w * 256))[lane31];
                #pragma unroll
                for (int i = 0; i < 8; i++)
                    a[i] += bf2f(v0[i]) + bf2f(v1[i]) + bf2f(v2[i]) + bf2f(v3[i]);
            }
            // write row: lane31 owns 16B segment sg=lane31, swizzled
            int r = wv * 16 + iw;
            int sgp = (lane31 & ~7) | ((lane31 ^ r) & 7);
            ushort8v o;
            #pragma unroll
            for (int i = 0; i < 8; i++) o[i] = f2bf(a[i]);
            *(ushort8v*)&Agg[r * 256 + sgp * 8] = o;
        }
    } else {  // K == 128
        for (int rd = 0; rd < 8; rd++) {
            const int iw = rd * 2 + hw;
            int cA = __shfl(cv, rd * 2);
            int cB = __shfl(cv, rd * 2 + 1);
            if (cA > MAXDEG) cA = MAXDEG;
            if (cB > MAXDEG) cB = MAXDEG;
            const int c    = hw ? cB : cA;
            const int cmax = cA > cB ? cA : cB;
            int node = m0 + wv * 16 + iw;
            if (node >= NNODES) node = NNODES - 1;
            float a0 = 0.f, a1 = 0.f, a2 = 0.f, a3 = 0.f;
            for (int j0 = 0; j0 < cmax; j0 += 4) {
                int4 e;
                if (j0 < 16) {
                    int src = iw * 4 + (j0 >> 2);
                    e.x = __shfl(elv.x, src); e.y = __shfl(elv.y, src);
                    e.z = __shfl(elv.z, src); e.w = __shfl(elv.w, src);
                } else {
                    e = ((const int4*)(elist + (size_t)node * MAXDEG))[j0 >> 2];
                }
                int rem = c - j0;
                ushort4 v0 = {0,0,0,0}, v1 = {0,0,0,0}, v2 = {0,0,0,0}, v3 = {0,0,0,0};
                if (rem > 0) v0 = ((const ushort4*)(h + (size_t)e.x * 128))[lane31];
                if (rem > 1) v1 = ((const ushort4*)(h + (size_t)e.y * 128))[lane31];
                if (rem > 2) v2 = ((const ushort4*)(h + (size_t)e.z * 128))[lane31];
                if (rem > 3) v3 = ((const ushort4*)(h + (size_t)e.w * 128))[lane31];
                a0 += bf2f(v0.x) + bf2f(v1.x) + bf2f(v2.x) + bf2f(v3.x);
                a1 += bf2f(v0.y) + bf2f(v1.y) + bf2f(v2.y) + bf2f(v3.y);
                a2 += bf2f(v0.z) + bf2f(v1.z) + bf2f(v2.z) + bf2f(v3.z);
                a3 += bf2f(v0.w) + bf2f(v1.w) + bf2f(v2.w) + bf2f(v3.w);
            }
            int r = wv * 16 + iw;
            int sg = lane31 >> 1;
            int sgp = (sg & ~7) | ((sg ^ r) & 7);
            ushort4 o; o.x = f2bf(a0); o.y = f2bf(a1); o.z = f2bf(a2); o.w = f2bf(a3);
            *(ushort4*)&Agg[r * 128 + sgp * 8 + (lane31 & 1) * 4] = o;
        }
    }

    // ---- dual-GEMM: barrier-free fragment loads ----
    f32x4 acc[4][4];
    #pragma unroll
    for (int i = 0; i < 4; i++)
        #pragma unroll
        for (int j = 0; j < 4; j++)
            acc[i][j] = (f32x4){0.f, 0.f, 0.f, 0.f};

    const int l15  = lane & 15;
    const int seg0 = lane >> 4;           // 0..3

    // Ws-half first (independent of gather): A = own h rows, B cols K..2K.
    // Fragments direct from global (L2/L3-resident).
    #pragma unroll
    for (int k0 = 0; k0 < K; k0 += BK) {
        #pragma unroll
        for (int half = 0; half < 2; half++) {
            const int seg = half * 4 + seg0;          // 0..7
            short8 af[4], bfr[4];
            #pragma unroll
            for (int mt = 0; mt < 4; mt++) {
                int grow = m0 + mt * 16 + l15; if (grow >= NNODES) grow = NNODES - 1;
                af[mt] = *(const short8*)(h + (size_t)grow * K + k0 + seg * 8);
            }
            #pragma unroll
            for (int nt = 0; nt < 4; nt++) {
                int nl = wv * 64 + nt * 16 + l15;
                bfr[nt] = *(const short8*)(B + (size_t)nl * Ktot + K + k0 + seg * 8);
            }
            #pragma unroll
            for (int mt = 0; mt < 4; mt++)
                #pragma unroll
                for (int nt = 0; nt < 4; nt++)
                    acc[mt][nt] = __builtin_amdgcn_mfma_f32_16x16x32_bf16(
                        af[mt], bfr[nt], acc[mt][nt], 0, 0, 0);
        }
    }

    __syncthreads();   // Agg tile complete & visible

    // Wr-half: A-frags from resident Agg (LDS, swizzled), B cols 0..K direct.
    #pragma unroll
    for (int k0 = 0; k0 < K; k0 += BK) {
        #pragma unroll
        for (int half = 0; half < 2; half++) {
            const int seg = half * 4 + seg0;
            short8 af[4], bfr[4];
            #pragma unroll
            for (int nt = 0; nt < 4; nt++) {
                int nl = wv * 64 + nt * 16 + l15;
                bfr[nt] = *(const short8*)(B + (size_t)nl * Ktot + k0 + seg * 8);
            }
            #pragma unroll
            for (int mt = 0; mt < 4; mt++) {
                int ml = mt * 16 + l15;
                int sg = (k0 >> 3) + seg;             // segment index within row
                int sgp = (sg & ~7) | ((sg ^ ml) & 7);
                af[mt] = *(const short8*)&Agg[ml * K + sgp * 8];
            }
            #pragma unroll
            for (int mt = 0; mt < 4; mt++)
                #pragma unroll
                for (int nt = 0; nt < 4; nt++)
                    acc[mt][nt] = __builtin_amdgcn_mfma_f32_16x16x32_bf16(
                        af[mt], bfr[nt], acc[mt][nt], 0, 0, 0);
        }
    }

    // ---- epilogue via LDS bounce: wide coalesced stores ----
    float* bounce = (float*)smem;
    float* wb = bounce + wv * (16 * 68);
    const int q    = lane & 3;       // 16-col segment in read phase
    const int rrow = lane >> 2;      // row 0..15 in read phase

    #pragma unroll
    for (int mt = 0; mt < 4; mt++) {
        __syncthreads();
        #pragma unroll
        for (int nt = 0; nt < 4; nt++)
            #pragma unroll
            for (int rr = 0; rr < 4; rr++)
                wb[((lane >> 4) * 4 + rr) * 68 + nt * 16 + (lane & 15)] = acc[mt][nt][rr];
        __syncthreads();

        int grow = m0 + mt * 16 + rrow;
        int gc   = wv * 64 + q * 16;
        float4 v[4];
        #pragma unroll
        for (int s = 0; s < 4; s++)
            v[s] = ((const float4*)(wb + rrow * 68 + q * 16))[s];

        if (grow < NNODES) {
            const float4* bv = (const float4*)(bias + gc);
            #pragma unroll
            for (int s = 0; s < 4; s++) {
                float4 b4 = bv[s];
                v[s].x = fmaxf(v[s].x + b4.x, 0.f);
                v[s].y = fmaxf(v[s].y + b4.y, 0.f);
                v[s].z = fmaxf(v[s].z + b4.z, 0.f);
                v[s].w = fmaxf(v[s].w + b4.w, 0.f);
            }
            if (MODE == 0) {
                ushort8v o0, o1;
                o0[0]=f2bf(v[0].x); o0[1]=f2bf(v[0].y); o0[2]=f2bf(v[0].z); o0[3]=f2bf(v[0].w);
                o0[4]=f2bf(v[1].x); o0[5]=f2bf(v[1].y); o0[6]=f2bf(v[1].z); o0[7]=f2bf(v[1].w);
                o1[0]=f2bf(v[2].x); o1[1]=f2bf(v[2].y); o1[2]=f2bf(v[2].z); o1[3]=f2bf(v[2].w);
                o1[4]=f2bf(v[3].x); o1[5]=f2bf(v[3].y); o1[6]=f2bf(v[3].z); o1[7]=f2bf(v[3].w);
                ushort8v* dst = (ushort8v*)(hout + (size_t)grow * HDIM + gc);
                dst[0] = o0; dst[1] = o1;
            } else {
                float4* xsp = (float4*)(xs + (size_t)grow * HDIM + gc);
                #pragma unroll
                for (int s = 0; s < 4; s++) xsp[s] = v[s];
                float* xo = (grow & 1) ? x2o : x1o;
                float4* xop = (float4*)(xo + (size_t)(grow >> 1) * HDIM + gc);
                #pragma unroll
                for (int s = 0; s < 4; s++) xop[s] = v[s];
                // head partial over this 64-col slice
                const float* wsp = (grow & 1) ? Wsp2 : Wsp1;
                const float4* wv4 = (const float4*)(wsp + gc);
                float p = 0.f;
                #pragma unroll
                for (int s = 0; s < 4; s++) {
                    float4 w4 = wv4[s];
                    p += v[s].x * w4.x + v[s].y * w4.y + v[s].z * w4.z + v[s].w * w4.w;
                }
                p += __shfl_xor(p, 1);
                p += __shfl_xor(p, 2);
                if (q == 0) atomicAdd(&spart[grow], p);
            }
        }
    }
}

// ---------------- head finalize ---------------------------------------------
__global__ void finalize_kernel(const float* __restrict__ spart, const float* __restrict__ bsp1,
                                const float* __restrict__ bsp2, const float* __restrict__ Wl,
                                const float* __restrict__ bl, float* __restrict__ y) {
    int p = blockIdx.x * 256 + threadIdx.x;
    if (p < NNODES / 2) {
        float s1 = spart[2 * p]     + bsp1[0]; s1 = s1 > 0.f ? s1 : 0.f;
        float s2 = spart[2 * p + 1] + bsp2[0]; s2 = s2 > 0.f ? s2 : 0.f;
        float t = s1 * Wl[0] + s2 * Wl[1] + bl[0];
        y[p] = 1.f / (1.f + expf(-t));
    }
}

extern "C" void kernel_launch(void* const* d_in, const int* in_sizes, int n_in,
                              void* d_out, int out_size, void* d_ws, size_t ws_size,
                              hipStream_t stream) {
    const float* x    = (const float*)d_in[0];
    const int*   ei   = (const int*)d_in[1];
    const float* Wr0  = (const float*)d_in[3];
    const float* br0  = (const float*)d_in[4];
    const float* Ws0  = (const float*)d_in[5];
    const float* Wr1  = (const float*)d_in[6];
    const float* br1  = (const float*)d_in[7];
    const float* Ws1  = (const float*)d_in[8];
    const float* Wr2  = (const float*)d_in[9];
    const float* br2  = (const float*)d_in[10];
    const float* Ws2  = (const float*)d_in[11];
    const float* Wsp1 = (const float*)d_in[12];
    const float* bsp1 = (const float*)d_in[13];
    const float* Wsp2 = (const float*)d_in[14];
    const float* bsp2 = (const float*)d_in[15];
    const float* Wl   = (const float*)d_in[16];
    const float* bl   = (const float*)d_in[17];

    char* ws = (char*)d_ws;
    size_t off = 0;
    auto alloc = [&](size_t bytes) -> void* {
        void* p = ws + off;
        off += (bytes + 255) & ~(size_t)255;
        return p;
    };
    int*            cnt   = (int*)alloc((size_t)NNODES * 4);          // zeroed
    float*          spart = (float*)alloc((size_t)NNODES * 4);        // zeroed (adjacent)
    size_t zero_bytes = off;
    int*            elist = (int*)alloc((size_t)NNODES * MAXDEG * 4);
    unsigned short* xb    = (unsigned short*)alloc((size_t)NNODES * INDIM * 2);
    unsigned short* hA    = (unsigned short*)alloc((size_t)NNODES * HDIM * 2);
    unsigned short* hB    = (unsigned short*)alloc((size_t)NNODES * HDIM * 2);
    unsigned short* B0    = (unsigned short*)alloc((size_t)HDIM * 2 * INDIM * 2);
    unsigned short* B1    = (unsigned short*)alloc((size_t)HDIM * 2 * HDIM * 2);
    unsigned short* B2    = (unsigned short*)alloc((size_t)HDIM * 2 * HDIM * 2);

    // d_out layout: y (50000) | xs (50000*512) | x1 (50000*256) | x2 (50000*256)
    float* y  = (float*)d_out;
    float* xs = y + 50000;
    float* x1 = xs + (size_t)50000 * 512;
    float* x2 = x1 + (size_t)50000 * 256;

    hipMemsetAsync(ws, 0, zero_bytes, stream);   // cnt + spart
    prep_kernel<<<PREP_BLOCKS, 256, 0, stream>>>(x, xb, Wr0, Ws0, B0, Wr1, Ws1, B1,
                                                 Wr2, Ws2, B2, ei, cnt, elist);

    // layer 0: fused gather(from bf16 x) + dual-GEMM, K=128
    fused_gconv<0, 128><<<MTILES, 256, 0, stream>>>(xb, cnt, elist, B0, br0, hA,
                                                    nullptr, nullptr, nullptr,
                                                    nullptr, nullptr, nullptr);
    // layer 1: K=256
    fused_gconv<0, 256><<<MTILES, 256, 0, stream>>>(hA, cnt, elist, B1, br1, hB,
                                                    nullptr, nullptr, nullptr,
                                                    nullptr, nullptr, nullptr);
    // layer 2: K=256, fp32 outputs straight into d_out + fused head partials
    fused_gconv<1, 256><<<MTILES, 256, 0, stream>>>(hB, cnt, elist, B2, br2, nullptr,
                                                    xs, x1, x2, Wsp1, Wsp2, spart);
    // head finalize
    finalize_kernel<<<(NNODES / 2 + 255) / 256, 256, 0, stream>>>(
        spart, bsp1, bsp2, Wl, bl, y);
}

// Round 4
// 625.870 us; speedup vs baseline: 1.0652x; 1.0652x over previous
//
#include <hip/hip_runtime.h>
#include <hip/hip_bf16.h>
#include <math.h>

#define NNODES 100000
#define NEDGES 400000
#define INDIM  128
#define HDIM   256
#define MAXDEG 32

#define BM 64
#define BN 256
#define MTILES 1563           // ceil(NNODES/64)

typedef __attribute__((ext_vector_type(8))) short short8;
typedef __attribute__((ext_vector_type(8))) unsigned short ushort8v;
typedef __attribute__((ext_vector_type(4))) float f32x4;

__device__ __forceinline__ float bf2f(unsigned short u) {
    union { unsigned int i; float f; } v; v.i = ((unsigned int)u) << 16; return v.f;
}
__device__ __forceinline__ unsigned short f2bf(float f) {
    union { float f; unsigned int i; } v; v.f = f;
    unsigned int r = v.i + 0x7fffu + ((v.i >> 16) & 1u);   // RNE
    return (unsigned short)(r >> 16);
}

__device__ __forceinline__ void async_load16(const void* g, void* l) {
    __builtin_amdgcn_global_load_lds(
        (const __attribute__((address_space(1))) unsigned int*)g,
        (__attribute__((address_space(3))) unsigned int*)l,
        16, 0, 0);
}

// ---------------- fused prep: convert_x + 3x convert_w + build_elist --------
#define XB_BLOCKS 12500                     // NNODES*INDIM/4 / 256
#define W0_BLOCKS 256                       // HDIM*2*INDIM / 256
#define W1_BLOCKS 512                       // HDIM*2*HDIM / 256
#define EL_BLOCKS 1563                      // ceil(NEDGES/256)
#define PREP_BLOCKS (XB_BLOCKS + W0_BLOCKS + 2 * W1_BLOCKS + EL_BLOCKS)

__global__ void prep_kernel(const float* __restrict__ x, unsigned short* __restrict__ xb,
                            const float* __restrict__ Wr0, const float* __restrict__ Ws0,
                            unsigned short* __restrict__ B0,
                            const float* __restrict__ Wr1, const float* __restrict__ Ws1,
                            unsigned short* __restrict__ B1,
                            const float* __restrict__ Wr2, const float* __restrict__ Ws2,
                            unsigned short* __restrict__ B2,
                            const int* __restrict__ ei, int* __restrict__ cnt,
                            int* __restrict__ elist) {
    int b = blockIdx.x;
    if (b < XB_BLOCKS) {
        int i = b * 256 + threadIdx.x;
        float4 v = ((const float4*)x)[i];
        ushort4 o; o.x = f2bf(v.x); o.y = f2bf(v.y); o.z = f2bf(v.z); o.w = f2bf(v.w);
        ((ushort4*)xb)[i] = o;
        return;
    }
    b -= XB_BLOCKS;
    if (b < W0_BLOCKS + 2 * W1_BLOCKS) {
        const float *Wr, *Ws; unsigned short* B; int K;
        if (b < W0_BLOCKS)               { Wr = Wr0; Ws = Ws0; B = B0; K = INDIM; }
        else if (b < W0_BLOCKS + W1_BLOCKS) { Wr = Wr1; Ws = Ws1; B = B1; K = HDIM; b -= W0_BLOCKS; }
        else                              { Wr = Wr2; Ws = Ws2; B = B2; K = HDIM; b -= W0_BLOCKS + W1_BLOCKS; }
        int idx = b * 256 + threadIdx.x;
        int n = idx / (2 * K);
        int k = idx - n * 2 * K;
        float v = (k < K) ? Wr[n * K + k] : Ws[n * K + (k - K)];
        B[idx] = f2bf(v);
        return;
    }
    b -= W0_BLOCKS + 2 * W1_BLOCKS;
    int e = b * 256 + threadIdx.x;
    if (e < NEDGES) {
        int d = ei[NEDGES + e];            // dst
        int s = ei[e];                     // src
        int pos = atomicAdd(&cnt[d], 1);
        if (pos < MAXDEG) elist[d * MAXDEG + pos] = s;
    }
}

// ---------------- fused gather + dual-GEMM + bias + relu --------------------
// ONE-BARRIER STRUCTURE:
//   t=0 : issue async global_load_lds for the ENTIRE A2 tile (own h rows,
//         [64][K], inverse-swizzled source, linear LDS dest) -> in flight
//         during the whole gather.
//   gather: neighbor sums into swizzled Agg tile ([64][K] LDS).
//   ONE __syncthreads + s_waitcnt vmcnt(0).
//   K-loop: ZERO barriers. A-frags (both halves) from resident LDS via
//         swizzled ds_read_b128; B-frags DIRECT from global (B is 256KB,
//         L2-hot, address-static -> compiler hoists across the unrolled loop).
//   epilogue: LDS-bounce coalesced stores (as before).
// LDS: 2*64*K*2 bytes = 64KB (K=256) / 32KB (K=128) -> 2 blocks/CU.
template<int MODE, int K>
__global__ __launch_bounds__(256, 2)
void fused_gconv(const unsigned short* __restrict__ h,
                 const int* __restrict__ cnt, const int* __restrict__ elist,
                 const unsigned short* __restrict__ B, const float* __restrict__ bias,
                 unsigned short* __restrict__ hout,
                 float* __restrict__ xs, float* __restrict__ x1o, float* __restrict__ x2o,
                 const float* __restrict__ Wsp1, const float* __restrict__ Wsp2,
                 float* __restrict__ spart) {
    __shared__ __align__(16) unsigned char smem[64 * K * 2 * 2];
    unsigned short* Agg  = (unsigned short*)smem;                  // [64][K] swizzled
    unsigned short* A2sh = (unsigned short*)(smem + 64 * K * 2);   // [64][K] swizzled

    const int tid  = threadIdx.x;
    const int lane = tid & 63;
    const int wv   = tid >> 6;            // wave: rows wv*16.. in gather, cols wv*64.. in GEMM
    const int m0   = blockIdx.x * BM;
    constexpr int Ktot = 2 * K;
    constexpr int SEGS = K / 8;           // 16B segments per row

    // ---- issue cnt + elist prefetch (to VGPRs) first ----
    const int lane31 = lane & 31;
    const int hw     = lane >> 5;
    int pn = m0 + wv * 16 + (lane >> 2);
    if (pn >= NNODES) pn = NNODES - 1;
    const int4 elv = ((const int4*)(elist + (size_t)pn * MAXDEG))[lane & 3];  // covers deg<=16
    int cnode = m0 + wv * 16 + (lane & 15);
    if (cnode >= NNODES) cnode = NNODES - 1;
    const int cv = cnt[cnode];

    // ---- stage ENTIRE A2 tile asynchronously (lands during gather) ----
    // LDS dest linear in (row, seg); global source seg inverse-swizzled so a
    // swizzled read matches (XOR involution within 8-seg stripes).
    #pragma unroll
    for (int it = 0; it < (64 * SEGS) / 256; it++) {
        int idx = it * 256 + tid;
        int row = idx / SEGS, seg = idx % SEGS;
        int gseg = (seg & ~7) | ((seg ^ (row & 7)) & 7);
        int grow = m0 + row; if (grow >= NNODES) grow = NNODES - 1;
        async_load16(h + (size_t)grow * K + gseg * 8, &A2sh[idx * 8]);
    }

    // ---- gather phase: 2 nodes per wave per round, 8 rounds ----
    if constexpr (K == 256) {
        for (int rd = 0; rd < 8; rd++) {
            const int iw = rd * 2 + hw;                 // in-block-wave node 0..15
            int cA = __shfl(cv, rd * 2);                // convergent: all shfl valid
            int cB = __shfl(cv, rd * 2 + 1);
            if (cA > MAXDEG) cA = MAXDEG;
            if (cB > MAXDEG) cB = MAXDEG;
            const int c    = hw ? cB : cA;
            const int cmax = cA > cB ? cA : cB;         // wave-uniform trip count
            int node = m0 + wv * 16 + iw;
            if (node >= NNODES) node = NNODES - 1;
            float a[8];
            #pragma unroll
            for (int i = 0; i < 8; i++) a[i] = 0.f;
            for (int j0 = 0; j0 < cmax; j0 += 4) {
                int4 e;
                if (j0 < 16) {
                    int src = iw * 4 + (j0 >> 2);
                    e.x = __shfl(elv.x, src); e.y = __shfl(elv.y, src);
                    e.z = __shfl(elv.z, src); e.w = __shfl(elv.w, src);
                } else {
                    e = ((const int4*)(elist + (size_t)node * MAXDEG))[j0 >> 2];
                }
                int rem = c - j0;
                ushort8v v0 = {0,0,0,0,0,0,0,0}, v1 = v0, v2 = v0, v3 = v0;
                if (rem > 0) v0 = ((const ushort8v*)(h + (size_t)e.x * 256))[lane31];
                if (rem > 1) v1 = ((const ushort8v*)(h + (size_t)e.y * 256))[lane31];
                if (rem > 2) v2 = ((const ushort8v*)(h + (size_t)e.z * 256))[lane31];
                if (rem > 3) v3 = ((const ushort8v*)(h + (size_t)e.w * 256))[lane31];
                #pragma unroll
                for (int i = 0; i < 8; i++)
                    a[i] += bf2f(v0[i]) + bf2f(v1[i]) + bf2f(v2[i]) + bf2f(v3[i]);
            }
            int r = wv * 16 + iw;
            int sgp = (lane31 & ~7) | ((lane31 ^ r) & 7);
            ushort8v o;
            #pragma unroll
            for (int i = 0; i < 8; i++) o[i] = f2bf(a[i]);
            *(ushort8v*)&Agg[r * 256 + sgp * 8] = o;
        }
    } else {  // K == 128
        for (int rd = 0; rd < 8; rd++) {
            const int iw = rd * 2 + hw;
            int cA = __shfl(cv, rd * 2);
            int cB = __shfl(cv, rd * 2 + 1);
            if (cA > MAXDEG) cA = MAXDEG;
            if (cB > MAXDEG) cB = MAXDEG;
            const int c    = hw ? cB : cA;
            const int cmax = cA > cB ? cA : cB;
            int node = m0 + wv * 16 + iw;
            if (node >= NNODES) node = NNODES - 1;
            float a0 = 0.f, a1 = 0.f, a2 = 0.f, a3 = 0.f;
            for (int j0 = 0; j0 < cmax; j0 += 4) {
                int4 e;
                if (j0 < 16) {
                    int src = iw * 4 + (j0 >> 2);
                    e.x = __shfl(elv.x, src); e.y = __shfl(elv.y, src);
                    e.z = __shfl(elv.z, src); e.w = __shfl(elv.w, src);
                } else {
                    e = ((const int4*)(elist + (size_t)node * MAXDEG))[j0 >> 2];
                }
                int rem = c - j0;
                ushort4 v0 = {0,0,0,0}, v1 = {0,0,0,0}, v2 = {0,0,0,0}, v3 = {0,0,0,0};
                if (rem > 0) v0 = ((const ushort4*)(h + (size_t)e.x * 128))[lane31];
                if (rem > 1) v1 = ((const ushort4*)(h + (size_t)e.y * 128))[lane31];
                if (rem > 2) v2 = ((const ushort4*)(h + (size_t)e.z * 128))[lane31];
                if (rem > 3) v3 = ((const ushort4*)(h + (size_t)e.w * 128))[lane31];
                a0 += bf2f(v0.x) + bf2f(v1.x) + bf2f(v2.x) + bf2f(v3.x);
                a1 += bf2f(v0.y) + bf2f(v1.y) + bf2f(v2.y) + bf2f(v3.y);
                a2 += bf2f(v0.z) + bf2f(v1.z) + bf2f(v2.z) + bf2f(v3.z);
                a3 += bf2f(v0.w) + bf2f(v1.w) + bf2f(v2.w) + bf2f(v3.w);
            }
            int r = wv * 16 + iw;
            int sg = lane31 >> 1;
            int sgp = (sg & ~7) | ((sg ^ r) & 7);
            ushort4 o; o.x = f2bf(a0); o.y = f2bf(a1); o.z = f2bf(a2); o.w = f2bf(a3);
            *(ushort4*)&Agg[r * 128 + sgp * 8 + (lane31 & 1) * 4] = o;
        }
    }

    // ---- the ONE synchronization point: Agg written, A2 landed ----
    __syncthreads();

    // ---- dual-GEMM K-loop: barrier-free, fully unrolled ----
    f32x4 acc[4][4];
    #pragma unroll
    for (int i = 0; i < 4; i++)
        #pragma unroll
        for (int j = 0; j < 4; j++)
            acc[i][j] = (f32x4){0.f, 0.f, 0.f, 0.f};

    const int l15  = lane & 15;
    const int seg0 = lane >> 4;           // 0..3

    #pragma unroll
    for (int k0 = 0; k0 < K; k0 += 64) {
        #pragma unroll
        for (int half = 0; half < 2; half++) {
            const int sg = (k0 >> 3) + half * 4 + seg0;   // global 16B-seg index 0..SEGS-1
            short8 afr[4], afs[4], bwr[4], bws[4];
            // B fragments direct from global (L2-hot), both halves
            #pragma unroll
            for (int nt = 0; nt < 4; nt++) {
                int nl = wv * 64 + nt * 16 + l15;
                bwr[nt] = *(const short8*)(B + (size_t)nl * Ktot + sg * 8);
                bws[nt] = *(const short8*)(B + (size_t)nl * Ktot + K + sg * 8);
            }
            // A fragments from resident LDS (swizzled)
            #pragma unroll
            for (int mt = 0; mt < 4; mt++) {
                int ml  = mt * 16 + l15;
                int sgp = (sg & ~7) | ((sg ^ ml) & 7);
                afr[mt] = *(const short8*)&Agg [ml * K + sgp * 8];
                afs[mt] = *(const short8*)&A2sh[ml * K + sgp * 8];
            }
            #pragma unroll
            for (int mt = 0; mt < 4; mt++)
                #pragma unroll
                for (int nt = 0; nt < 4; nt++)
                    acc[mt][nt] = __builtin_amdgcn_mfma_f32_16x16x32_bf16(
                        afr[mt], bwr[nt], acc[mt][nt], 0, 0, 0);
            #pragma unroll
            for (int mt = 0; mt < 4; mt++)
                #pragma unroll
                for (int nt = 0; nt < 4; nt++)
                    acc[mt][nt] = __builtin_amdgcn_mfma_f32_16x16x32_bf16(
                        afs[mt], bws[nt], acc[mt][nt], 0, 0, 0);
        }
    }

    // ---- epilogue via LDS bounce: wide coalesced stores ----
    float* bounce = (float*)smem;
    float* wb = bounce + wv * (16 * 68);
    const int q    = lane & 3;       // 16-col segment in read phase
    const int rrow = lane >> 2;      // row 0..15 in read phase

    #pragma unroll
    for (int mt = 0; mt < 4; mt++) {
        __syncthreads();
        #pragma unroll
        for (int nt = 0; nt < 4; nt++)
            #pragma unroll
            for (int rr = 0; rr < 4; rr++)
                wb[((lane >> 4) * 4 + rr) * 68 + nt * 16 + (lane & 15)] = acc[mt][nt][rr];
        __syncthreads();

        int grow = m0 + mt * 16 + rrow;
        int gc   = wv * 64 + q * 16;
        float4 v[4];
        #pragma unroll
        for (int s = 0; s < 4; s++)
            v[s] = ((const float4*)(wb + rrow * 68 + q * 16))[s];

        if (grow < NNODES) {
            const float4* bv = (const float4*)(bias + gc);
            #pragma unroll
            for (int s = 0; s < 4; s++) {
                float4 b4 = bv[s];
                v[s].x = fmaxf(v[s].x + b4.x, 0.f);
                v[s].y = fmaxf(v[s].y + b4.y, 0.f);
                v[s].z = fmaxf(v[s].z + b4.z, 0.f);
                v[s].w = fmaxf(v[s].w + b4.w, 0.f);
            }
            if (MODE == 0) {
                ushort8v o0, o1;
                o0[0]=f2bf(v[0].x); o0[1]=f2bf(v[0].y); o0[2]=f2bf(v[0].z); o0[3]=f2bf(v[0].w);
                o0[4]=f2bf(v[1].x); o0[5]=f2bf(v[1].y); o0[6]=f2bf(v[1].z); o0[7]=f2bf(v[1].w);
                o1[0]=f2bf(v[2].x); o1[1]=f2bf(v[2].y); o1[2]=f2bf(v[2].z); o1[3]=f2bf(v[2].w);
                o1[4]=f2bf(v[3].x); o1[5]=f2bf(v[3].y); o1[6]=f2bf(v[3].z); o1[7]=f2bf(v[3].w);
                ushort8v* dst = (ushort8v*)(hout + (size_t)grow * HDIM + gc);
                dst[0] = o0; dst[1] = o1;
            } else {
                float4* xsp = (float4*)(xs + (size_t)grow * HDIM + gc);
                #pragma unroll
                for (int s = 0; s < 4; s++) xsp[s] = v[s];
                float* xo = (grow & 1) ? x2o : x1o;
                float4* xop = (float4*)(xo + (size_t)(grow >> 1) * HDIM + gc);
                #pragma unroll
                for (int s = 0; s < 4; s++) xop[s] = v[s];
                // head partial over this 64-col slice
                const float* wsp = (grow & 1) ? Wsp2 : Wsp1;
                const float4* wv4 = (const float4*)(wsp + gc);
                float p = 0.f;
                #pragma unroll
                for (int s = 0; s < 4; s++) {
                    float4 w4 = wv4[s];
                    p += v[s].x * w4.x + v[s].y * w4.y + v[s].z * w4.z + v[s].w * w4.w;
                }
                p += __shfl_xor(p, 1);
                p += __shfl_xor(p, 2);
                if (q == 0) atomicAdd(&spart[grow], p);
            }
        }
    }
}

// ---------------- head finalize ---------------------------------------------
__global__ void finalize_kernel(const float* __restrict__ spart, const float* __restrict__ bsp1,
                                const float* __restrict__ bsp2, const float* __restrict__ Wl,
                                const float* __restrict__ bl, float* __restrict__ y) {
    int p = blockIdx.x * 256 + threadIdx.x;
    if (p < NNODES / 2) {
        float s1 = spart[2 * p]     + bsp1[0]; s1 = s1 > 0.f ? s1 : 0.f;
        float s2 = spart[2 * p + 1] + bsp2[0]; s2 = s2 > 0.f ? s2 : 0.f;
        float t = s1 * Wl[0] + s2 * Wl[1] + bl[0];
        y[p] = 1.f / (1.f + expf(-t));
    }
}

extern "C" void kernel_launch(void* const* d_in, const int* in_sizes, int n_in,
                              void* d_out, int out_size, void* d_ws, size_t ws_size,
                              hipStream_t stream) {
    const float* x    = (const float*)d_in[0];
    const int*   ei   = (const int*)d_in[1];
    const float* Wr0  = (const float*)d_in[3];
    const float* br0  = (const float*)d_in[4];
    const float* Ws0  = (const float*)d_in[5];
    const float* Wr1  = (const float*)d_in[6];
    const float* br1  = (const float*)d_in[7];
    const float* Ws1  = (const float*)d_in[8];
    const float* Wr2  = (const float*)d_in[9];
    const float* br2  = (const float*)d_in[10];
    const float* Ws2  = (const float*)d_in[11];
    const float* Wsp1 = (const float*)d_in[12];
    const float* bsp1 = (const float*)d_in[13];
    const float* Wsp2 = (const float*)d_in[14];
    const float* bsp2 = (const float*)d_in[15];
    const float* Wl   = (const float*)d_in[16];
    const float* bl   = (const float*)d_in[17];

    char* ws = (char*)d_ws;
    size_t off = 0;
    auto alloc = [&](size_t bytes) -> void* {
        void* p = ws + off;
        off += (bytes + 255) & ~(size_t)255;
        return p;
    };
    int*            cnt   = (int*)alloc((size_t)NNODES * 4);          // zeroed
    float*          spart = (float*)alloc((size_t)NNODES * 4);        // zeroed (adjacent)
    size_t zero_bytes = off;
    int*            elist = (int*)alloc((size_t)NNODES * MAXDEG * 4);
    unsigned short* xb    = (unsigned short*)alloc((size_t)NNODES * INDIM * 2);
    unsigned short* hA    = (unsigned short*)alloc((size_t)NNODES * HDIM * 2);
    unsigned short* hB    = (unsigned short*)alloc((size_t)NNODES * HDIM * 2);
    unsigned short* B0    = (unsigned short*)alloc((size_t)HDIM * 2 * INDIM * 2);
    unsigned short* B1    = (unsigned short*)alloc((size_t)HDIM * 2 * HDIM * 2);
    unsigned short* B2    = (unsigned short*)alloc((size_t)HDIM * 2 * HDIM * 2);

    // d_out layout: y (50000) | xs (50000*512) | x1 (50000*256) | x2 (50000*256)
    float* y  = (float*)d_out;
    float* xs = y + 50000;
    float* x1 = xs + (size_t)50000 * 512;
    float* x2 = x1 + (size_t)50000 * 256;

    hipMemsetAsync(ws, 0, zero_bytes, stream);   // cnt + spart
    prep_kernel<<<PREP_BLOCKS, 256, 0, stream>>>(x, xb, Wr0, Ws0, B0, Wr1, Ws1, B1,
                                                 Wr2, Ws2, B2, ei, cnt, elist);

    // layer 0: fused gather(from bf16 x) + dual-GEMM, K=128
    fused_gconv<0, 128><<<MTILES, 256, 0, stream>>>(xb, cnt, elist, B0, br0, hA,
                                                    nullptr, nullptr, nullptr,
                                                    nullptr, nullptr, nullptr);
    // layer 1: K=256
    fused_gconv<0, 256><<<MTILES, 256, 0, stream>>>(hA, cnt, elist, B1, br1, hB,
                                                    nullptr, nullptr, nullptr,
                                                    nullptr, nullptr, nullptr);
    // layer 2: K=256, fp32 outputs straight into d_out + fused head partials
    fused_gconv<1, 256><<<MTILES, 256, 0, stream>>>(hB, cnt, elist, B2, br2, nullptr,
                                                    xs, x1, x2, Wsp1, Wsp2, spart);
    // head finalize
    finalize_kernel<<<(NNODES / 2 + 255) / 256, 256, 0, stream>>>(
        spart, bsp1, bsp2, Wl, bl, y);
}

// Round 5
// 554.639 us; speedup vs baseline: 1.2020x; 1.1284x over previous
//
#include <hip/hip_runtime.h>
#include <hip/hip_bf16.h>
#include <math.h>

#define NNODES 100000
#define NEDGES 400000
#define INDIM  128
#define HDIM   256
#define MAXDEG 32

#define BM 64
#define BN 256
#define MTILES 1563           // ceil(NNODES/64)

typedef __attribute__((ext_vector_type(8))) short short8;
typedef __attribute__((ext_vector_type(8))) unsigned short ushort8v;
typedef __attribute__((ext_vector_type(4))) float f32x4;

__device__ __forceinline__ float bf2f(unsigned short u) {
    union { unsigned int i; float f; } v; v.i = ((unsigned int)u) << 16; return v.f;
}
__device__ __forceinline__ unsigned short f2bf(float f) {
    union { float f; unsigned int i; } v; v.f = f;
    unsigned int r = v.i + 0x7fffu + ((v.i >> 16) & 1u);   // RNE
    return (unsigned short)(r >> 16);
}

__device__ __forceinline__ void async_load16(const void* g, void* l) {
    __builtin_amdgcn_global_load_lds(
        (const __attribute__((address_space(1))) unsigned int*)g,
        (__attribute__((address_space(3))) unsigned int*)l,
        16, 0, 0);
}

__device__ __forceinline__ int4 shfl4(const int4 v, int src) {
    int4 r;
    r.x = __shfl(v.x, src); r.y = __shfl(v.y, src);
    r.z = __shfl(v.z, src); r.w = __shfl(v.w, src);
    return r;
}

// ---------------- fused prep: convert_x + 3x convert_w + build_elist --------
#define XB_BLOCKS 12500                     // NNODES*INDIM/4 / 256
#define W0_BLOCKS 256                       // HDIM*2*INDIM / 256
#define W1_BLOCKS 512                       // HDIM*2*HDIM / 256
#define EL_BLOCKS 1563                      // ceil(NEDGES/256)
#define PREP_BLOCKS (XB_BLOCKS + W0_BLOCKS + 2 * W1_BLOCKS + EL_BLOCKS)

__global__ void prep_kernel(const float* __restrict__ x, unsigned short* __restrict__ xb,
                            const float* __restrict__ Wr0, const float* __restrict__ Ws0,
                            unsigned short* __restrict__ B0,
                            const float* __restrict__ Wr1, const float* __restrict__ Ws1,
                            unsigned short* __restrict__ B1,
                            const float* __restrict__ Wr2, const float* __restrict__ Ws2,
                            unsigned short* __restrict__ B2,
                            const int* __restrict__ ei, int* __restrict__ cnt,
                            int* __restrict__ elist) {
    int b = blockIdx.x;
    if (b < XB_BLOCKS) {
        int i = b * 256 + threadIdx.x;
        float4 v = ((const float4*)x)[i];
        ushort4 o; o.x = f2bf(v.x); o.y = f2bf(v.y); o.z = f2bf(v.z); o.w = f2bf(v.w);
        ((ushort4*)xb)[i] = o;
        return;
    }
    b -= XB_BLOCKS;
    if (b < W0_BLOCKS + 2 * W1_BLOCKS) {
        const float *Wr, *Ws; unsigned short* B; int K;
        if (b < W0_BLOCKS)               { Wr = Wr0; Ws = Ws0; B = B0; K = INDIM; }
        else if (b < W0_BLOCKS + W1_BLOCKS) { Wr = Wr1; Ws = Ws1; B = B1; K = HDIM; b -= W0_BLOCKS; }
        else                              { Wr = Wr2; Ws = Ws2; B = B2; K = HDIM; b -= W0_BLOCKS + W1_BLOCKS; }
        int idx = b * 256 + threadIdx.x;
        int n = idx / (2 * K);
        int k = idx - n * 2 * K;
        float v = (k < K) ? Wr[n * K + k] : Ws[n * K + (k - K)];
        B[idx] = f2bf(v);
        return;
    }
    b -= W0_BLOCKS + 2 * W1_BLOCKS;
    int e = b * 256 + threadIdx.x;
    if (e < NEDGES) {
        int d = ei[NEDGES + e];            // dst
        int s = ei[e];                     // src
        int pos = atomicAdd(&cnt[d], 1);
        if (pos < MAXDEG) elist[d * MAXDEG + pos] = s;
    }
}

// ---------------- fused gather + dual-GEMM + bias + relu --------------------
// 512 threads (8 waves) per 64x256 tile.
//   - A2 tile staged once via global_load_lds (in flight during gather).
//   - gather: 8 nodes/wave, 4 rounds x 2 half-wave nodes; elist fully
//     register-resident (8 int4 slots/node, all 32 neighbors); 2-deep
//     neighbor batching (chunks 0+1 issued together).
//   - ONE barrier, then barrier-free dual-GEMM: A-frags from LDS,
//     B-frags direct from global (L2-hot).
// LDS: 2*64*K*2 = 64KB (K=256, 2 blk/CU = 16 waves) / 32KB (K=128, 4 blk/CU).
template<int MODE, int K>
__global__ __launch_bounds__(512, 4)
void fused_gconv(const unsigned short* __restrict__ h,
                 const int* __restrict__ cnt, const int* __restrict__ elist,
                 const unsigned short* __restrict__ B, const float* __restrict__ bias,
                 unsigned short* __restrict__ hout,
                 float* __restrict__ xs, float* __restrict__ x1o, float* __restrict__ x2o,
                 const float* __restrict__ Wsp1, const float* __restrict__ Wsp2,
                 float* __restrict__ spart) {
    __shared__ __align__(16) unsigned char smem[64 * K * 2 * 2];
    unsigned short* Agg  = (unsigned short*)smem;                  // [64][K] swizzled
    unsigned short* A2sh = (unsigned short*)(smem + 64 * K * 2);   // [64][K] swizzled

    const int tid  = threadIdx.x;
    const int lane = tid & 63;
    const int wv   = tid >> 6;            // 0..7: rows wv*8.. in gather, cols wv*32.. in GEMM
    const int m0   = blockIdx.x * BM;
    constexpr int Ktot = 2 * K;
    constexpr int SEGS = K / 8;           // 16B segments per row

    // ---- register prefetch: cnt + FULL elist rows (8 nodes x 8 int4) ----
    const int lane31 = lane & 31;
    const int hw     = lane >> 5;
    int pn = m0 + wv * 8 + (lane >> 3);
    if (pn >= NNODES) pn = NNODES - 1;
    const int4 elv = ((const int4*)(elist + (size_t)pn * MAXDEG))[lane & 7];
    int cnode = m0 + wv * 8 + (lane & 7);
    if (cnode >= NNODES) cnode = NNODES - 1;
    const int cv = cnt[cnode];

    // ---- stage ENTIRE A2 tile asynchronously (lands during gather) ----
    #pragma unroll
    for (int it = 0; it < (64 * SEGS) / 512; it++) {
        int idx = it * 512 + tid;
        int row = idx / SEGS, seg = idx % SEGS;
        int gseg = (seg & ~7) | ((seg ^ (row & 7)) & 7);
        int grow = m0 + row; if (grow >= NNODES) grow = NNODES - 1;
        async_load16(h + (size_t)grow * K + gseg * 8, &A2sh[idx * 8]);
    }

    // ---- gather phase: 2 nodes per wave per round, 4 rounds ----
    #pragma unroll
    for (int rd = 0; rd < 4; rd++) {
        const int iw = rd * 2 + hw;                 // in-wave node 0..7
        int cA = __shfl(cv, rd * 2);
        int cB = __shfl(cv, rd * 2 + 1);
        if (cA > MAXDEG) cA = MAXDEG;
        if (cB > MAXDEG) cB = MAXDEG;
        const int c    = hw ? cB : cA;
        const int cmax = cA > cB ? cA : cB;         // wave-uniform trip count
        const int4 e0 = shfl4(elv, iw * 8 + 0);     // neighbors 0..3
        const int4 e1 = shfl4(elv, iw * 8 + 1);     // neighbors 4..7

        if constexpr (K == 256) {
            float a[8];
            #pragma unroll
            for (int i = 0; i < 8; i++) a[i] = 0.f;
            ushort8v z = {0,0,0,0,0,0,0,0};
            ushort8v v0 = z, v1 = z, v2 = z, v3 = z;
            ushort8v w0 = z, w1 = z, w2 = z, w3 = z;
            if (c > 0) v0 = ((const ushort8v*)(h + (size_t)e0.x * 256))[lane31];
            if (c > 1) v1 = ((const ushort8v*)(h + (size_t)e0.y * 256))[lane31];
            if (c > 2) v2 = ((const ushort8v*)(h + (size_t)e0.z * 256))[lane31];
            if (c > 3) v3 = ((const ushort8v*)(h + (size_t)e0.w * 256))[lane31];
            if (cmax > 4) {                         // wave-uniform
                int r2 = c - 4;
                if (r2 > 0) w0 = ((const ushort8v*)(h + (size_t)e1.x * 256))[lane31];
                if (r2 > 1) w1 = ((const ushort8v*)(h + (size_t)e1.y * 256))[lane31];
                if (r2 > 2) w2 = ((const ushort8v*)(h + (size_t)e1.z * 256))[lane31];
                if (r2 > 3) w3 = ((const ushort8v*)(h + (size_t)e1.w * 256))[lane31];
            }
            #pragma unroll
            for (int i = 0; i < 8; i++)
                a[i] += (bf2f(v0[i]) + bf2f(v1[i]) + bf2f(v2[i]) + bf2f(v3[i]))
                      + (bf2f(w0[i]) + bf2f(w1[i]) + bf2f(w2[i]) + bf2f(w3[i]));
            for (int j0 = 8; j0 < cmax; j0 += 4) {  // rare tail (deg > 8)
                int4 e = shfl4(elv, iw * 8 + (j0 >> 2));
                int rem = c - j0;
                ushort8v t0 = z, t1 = z, t2 = z, t3 = z;
                if (rem > 0) t0 = ((const ushort8v*)(h + (size_t)e.x * 256))[lane31];
                if (rem > 1) t1 = ((const ushort8v*)(h + (size_t)e.y * 256))[lane31];
                if (rem > 2) t2 = ((const ushort8v*)(h + (size_t)e.z * 256))[lane31];
                if (rem > 3) t3 = ((const ushort8v*)(h + (size_t)e.w * 256))[lane31];
                #pragma unroll
                for (int i = 0; i < 8; i++)
                    a[i] += bf2f(t0[i]) + bf2f(t1[i]) + bf2f(t2[i]) + bf2f(t3[i]);
            }
            int r = wv * 8 + iw;
            int sgp = (lane31 & ~7) | ((lane31 ^ r) & 7);
            ushort8v o;
            #pragma unroll
            for (int i = 0; i < 8; i++) o[i] = f2bf(a[i]);
            *(ushort8v*)&Agg[r * 256 + sgp * 8] = o;
        } else {  // K == 128
            float a0 = 0.f, a1 = 0.f, a2 = 0.f, a3 = 0.f;
            ushort4 z = {0,0,0,0};
            ushort4 v0 = z, v1 = z, v2 = z, v3 = z;
            ushort4 w0 = z, w1 = z, w2 = z, w3 = z;
            if (c > 0) v0 = ((const ushort4*)(h + (size_t)e0.x * 128))[lane31];
            if (c > 1) v1 = ((const ushort4*)(h + (size_t)e0.y * 128))[lane31];
            if (c > 2) v2 = ((const ushort4*)(h + (size_t)e0.z * 128))[lane31];
            if (c > 3) v3 = ((const ushort4*)(h + (size_t)e0.w * 128))[lane31];
            if (cmax > 4) {
                int r2 = c - 4;
                if (r2 > 0) w0 = ((const ushort4*)(h + (size_t)e1.x * 128))[lane31];
                if (r2 > 1) w1 = ((const ushort4*)(h + (size_t)e1.y * 128))[lane31];
                if (r2 > 2) w2 = ((const ushort4*)(h + (size_t)e1.z * 128))[lane31];
                if (r2 > 3) w3 = ((const ushort4*)(h + (size_t)e1.w * 128))[lane31];
            }
            a0 += bf2f(v0.x) + bf2f(v1.x) + bf2f(v2.x) + bf2f(v3.x)
                + bf2f(w0.x) + bf2f(w1.x) + bf2f(w2.x) + bf2f(w3.x);
            a1 += bf2f(v0.y) + bf2f(v1.y) + bf2f(v2.y) + bf2f(v3.y)
                + bf2f(w0.y) + bf2f(w1.y) + bf2f(w2.y) + bf2f(w3.y);
            a2 += bf2f(v0.z) + bf2f(v1.z) + bf2f(v2.z) + bf2f(v3.z)
                + bf2f(w0.z) + bf2f(w1.z) + bf2f(w2.z) + bf2f(w3.z);
            a3 += bf2f(v0.w) + bf2f(v1.w) + bf2f(v2.w) + bf2f(v3.w)
                + bf2f(w0.w) + bf2f(w1.w) + bf2f(w2.w) + bf2f(w3.w);
            for (int j0 = 8; j0 < cmax; j0 += 4) {
                int4 e = shfl4(elv, iw * 8 + (j0 >> 2));
                int rem = c - j0;
                ushort4 t0 = z, t1 = z, t2 = z, t3 = z;
                if (rem > 0) t0 = ((const ushort4*)(h + (size_t)e.x * 128))[lane31];
                if (rem > 1) t1 = ((const ushort4*)(h + (size_t)e.y * 128))[lane31];
                if (rem > 2) t2 = ((const ushort4*)(h + (size_t)e.z * 128))[lane31];
                if (rem > 3) t3 = ((const ushort4*)(h + (size_t)e.w * 128))[lane31];
                a0 += bf2f(t0.x) + bf2f(t1.x) + bf2f(t2.x) + bf2f(t3.x);
                a1 += bf2f(t0.y) + bf2f(t1.y) + bf2f(t2.y) + bf2f(t3.y);
                a2 += bf2f(t0.z) + bf2f(t1.z) + bf2f(t2.z) + bf2f(t3.z);
                a3 += bf2f(t0.w) + bf2f(t1.w) + bf2f(t2.w) + bf2f(t3.w);
            }
            int r = wv * 8 + iw;
            int sg = lane31 >> 1;
            int sgp = (sg & ~7) | ((sg ^ r) & 7);
            ushort4 o; o.x = f2bf(a0); o.y = f2bf(a1); o.z = f2bf(a2); o.w = f2bf(a3);
            *(ushort4*)&Agg[r * 128 + sgp * 8 + (lane31 & 1) * 4] = o;
        }
    }

    // ---- the ONE synchronization point: Agg written, A2 landed ----
    __syncthreads();

    // ---- dual-GEMM K-loop: barrier-free, fully unrolled ----
    f32x4 acc[4][2];
    #pragma unroll
    for (int i = 0; i < 4; i++)
        #pragma unroll
        for (int j = 0; j < 2; j++)
            acc[i][j] = (f32x4){0.f, 0.f, 0.f, 0.f};

    const int l15  = lane & 15;
    const int seg0 = lane >> 4;           // 0..3

    #pragma unroll
    for (int k0 = 0; k0 < K; k0 += 64) {
        #pragma unroll
        for (int half = 0; half < 2; half++) {
            const int sg = (k0 >> 3) + half * 4 + seg0;   // 16B-seg index 0..SEGS-1
            short8 afr[4], afs[4], bwr[2], bws[2];
            #pragma unroll
            for (int nt = 0; nt < 2; nt++) {
                int nl = wv * 32 + nt * 16 + l15;
                bwr[nt] = *(const short8*)(B + (size_t)nl * Ktot + sg * 8);
                bws[nt] = *(const short8*)(B + (size_t)nl * Ktot + K + sg * 8);
            }
            #pragma unroll
            for (int mt = 0; mt < 4; mt++) {
                int ml  = mt * 16 + l15;
                int sgp = (sg & ~7) | ((sg ^ ml) & 7);
                afr[mt] = *(const short8*)&Agg [ml * K + sgp * 8];
                afs[mt] = *(const short8*)&A2sh[ml * K + sgp * 8];
            }
            #pragma unroll
            for (int mt = 0; mt < 4; mt++)
                #pragma unroll
                for (int nt = 0; nt < 2; nt++)
                    acc[mt][nt] = __builtin_amdgcn_mfma_f32_16x16x32_bf16(
                        afr[mt], bwr[nt], acc[mt][nt], 0, 0, 0);
            #pragma unroll
            for (int mt = 0; mt < 4; mt++)
                #pragma unroll
                for (int nt = 0; nt < 2; nt++)
                    acc[mt][nt] = __builtin_amdgcn_mfma_f32_16x16x32_bf16(
                        afs[mt], bws[nt], acc[mt][nt], 0, 0, 0);
        }
    }

    // ---- epilogue via LDS bounce: wave owns 64 rows x 32 cols ----
    float* bounce = (float*)smem;
    float* wb = bounce + wv * (16 * 40);   // 8 waves x 2560B = 20KB
    const int q    = lane & 3;             // 4-col segment pair in read phase
    const int rrow = lane >> 2;            // row 0..15 in read phase

    #pragma unroll
    for (int mt = 0; mt < 4; mt++) {
        __syncthreads();
        #pragma unroll
        for (int nt = 0; nt < 2; nt++)
            #pragma unroll
            for (int rr = 0; rr < 4; rr++)
                wb[((lane >> 4) * 4 + rr) * 40 + nt * 16 + l15] = acc[mt][nt][rr];
        __syncthreads();

        int grow = m0 + mt * 16 + rrow;
        int gc0  = wv * 32 + q * 4;
        int gc1  = gc0 + 16;
        float4 v0 = *(const float4*)(wb + rrow * 40 + q * 4);
        float4 v1 = *(const float4*)(wb + rrow * 40 + 16 + q * 4);

        if (grow < NNODES) {
            float4 b0 = *(const float4*)(bias + gc0);
            float4 b1 = *(const float4*)(bias + gc1);
            v0.x = fmaxf(v0.x + b0.x, 0.f); v0.y = fmaxf(v0.y + b0.y, 0.f);
            v0.z = fmaxf(v0.z + b0.z, 0.f); v0.w = fmaxf(v0.w + b0.w, 0.f);
            v1.x = fmaxf(v1.x + b1.x, 0.f); v1.y = fmaxf(v1.y + b1.y, 0.f);
            v1.z = fmaxf(v1.z + b1.z, 0.f); v1.w = fmaxf(v1.w + b1.w, 0.f);
            if (MODE == 0) {
                ushort4 o0, o1;
                o0.x = f2bf(v0.x); o0.y = f2bf(v0.y); o0.z = f2bf(v0.z); o0.w = f2bf(v0.w);
                o1.x = f2bf(v1.x); o1.y = f2bf(v1.y); o1.z = f2bf(v1.z); o1.w = f2bf(v1.w);
                *(ushort4*)(hout + (size_t)grow * HDIM + gc0) = o0;
                *(ushort4*)(hout + (size_t)grow * HDIM + gc1) = o1;
            } else {
                *(float4*)(xs + (size_t)grow * HDIM + gc0) = v0;
                *(float4*)(xs + (size_t)grow * HDIM + gc1) = v1;
                float* xo = (grow & 1) ? x2o : x1o;
                *(float4*)(xo + (size_t)(grow >> 1) * HDIM + gc0) = v0;
                *(float4*)(xo + (size_t)(grow >> 1) * HDIM + gc1) = v1;
                const float* wsp = (grow & 1) ? Wsp2 : Wsp1;
                float4 w0 = *(const float4*)(wsp + gc0);
                float4 w1 = *(const float4*)(wsp + gc1);
                float p = v0.x * w0.x + v0.y * w0.y + v0.z * w0.z + v0.w * w0.w
                        + v1.x * w1.x + v1.y * w1.y + v1.z * w1.z + v1.w * w1.w;
                p += __shfl_xor(p, 1);
                p += __shfl_xor(p, 2);
                if (q == 0) atomicAdd(&spart[grow], p);
            }
        }
    }
}

// ---------------- head finalize ---------------------------------------------
__global__ void finalize_kernel(const float* __restrict__ spart, const float* __restrict__ bsp1,
                                const float* __restrict__ bsp2, const float* __restrict__ Wl,
                                const float* __restrict__ bl, float* __restrict__ y) {
    int p = blockIdx.x * 256 + threadIdx.x;
    if (p < NNODES / 2) {
        float s1 = spart[2 * p]     + bsp1[0]; s1 = s1 > 0.f ? s1 : 0.f;
        float s2 = spart[2 * p + 1] + bsp2[0]; s2 = s2 > 0.f ? s2 : 0.f;
        float t = s1 * Wl[0] + s2 * Wl[1] + bl[0];
        y[p] = 1.f / (1.f + expf(-t));
    }
}

extern "C" void kernel_launch(void* const* d_in, const int* in_sizes, int n_in,
                              void* d_out, int out_size, void* d_ws, size_t ws_size,
                              hipStream_t stream) {
    const float* x    = (const float*)d_in[0];
    const int*   ei   = (const int*)d_in[1];
    const float* Wr0  = (const float*)d_in[3];
    const float* br0  = (const float*)d_in[4];
    const float* Ws0  = (const float*)d_in[5];
    const float* Wr1  = (const float*)d_in[6];
    const float* br1  = (const float*)d_in[7];
    const float* Ws1  = (const float*)d_in[8];
    const float* Wr2  = (const float*)d_in[9];
    const float* br2  = (const float*)d_in[10];
    const float* Ws2  = (const float*)d_in[11];
    const float* Wsp1 = (const float*)d_in[12];
    const float* bsp1 = (const float*)d_in[13];
    const float* Wsp2 = (const float*)d_in[14];
    const float* bsp2 = (const float*)d_in[15];
    const float* Wl   = (const float*)d_in[16];
    const float* bl   = (const float*)d_in[17];

    char* ws = (char*)d_ws;
    size_t off = 0;
    auto alloc = [&](size_t bytes) -> void* {
        void* p = ws + off;
        off += (bytes + 255) & ~(size_t)255;
        return p;
    };
    int*            cnt   = (int*)alloc((size_t)NNODES * 4);          // zeroed
    float*          spart = (float*)alloc((size_t)NNODES * 4);        // zeroed (adjacent)
    size_t zero_bytes = off;
    int*            elist = (int*)alloc((size_t)NNODES * MAXDEG * 4);
    unsigned short* xb    = (unsigned short*)alloc((size_t)NNODES * INDIM * 2);
    unsigned short* hA    = (unsigned short*)alloc((size_t)NNODES * HDIM * 2);
    unsigned short* hB    = (unsigned short*)alloc((size_t)NNODES * HDIM * 2);
    unsigned short* B0    = (unsigned short*)alloc((size_t)HDIM * 2 * INDIM * 2);
    unsigned short* B1    = (unsigned short*)alloc((size_t)HDIM * 2 * HDIM * 2);
    unsigned short* B2    = (unsigned short*)alloc((size_t)HDIM * 2 * HDIM * 2);

    // d_out layout: y (50000) | xs (50000*512) | x1 (50000*256) | x2 (50000*256)
    float* y  = (float*)d_out;
    float* xs = y + 50000;
    float* x1 = xs + (size_t)50000 * 512;
    float* x2 = x1 + (size_t)50000 * 256;

    hipMemsetAsync(ws, 0, zero_bytes, stream);   // cnt + spart
    prep_kernel<<<PREP_BLOCKS, 256, 0, stream>>>(x, xb, Wr0, Ws0, B0, Wr1, Ws1, B1,
                                                 Wr2, Ws2, B2, ei, cnt, elist);

    // layer 0: fused gather(from bf16 x) + dual-GEMM, K=128
    fused_gconv<0, 128><<<MTILES, 512, 0, stream>>>(xb, cnt, elist, B0, br0, hA,
                                                    nullptr, nullptr, nullptr,
                                                    nullptr, nullptr, nullptr);
    // layer 1: K=256
    fused_gconv<0, 256><<<MTILES, 512, 0, stream>>>(hA, cnt, elist, B1, br1, hB,
                                                    nullptr, nullptr, nullptr,
                                                    nullptr, nullptr, nullptr);
    // layer 2: K=256, fp32 outputs straight into d_out + fused head partials
    fused_gconv<1, 256><<<MTILES, 512, 0, stream>>>(hB, cnt, elist, B2, br2, nullptr,
                                                    xs, x1, x2, Wsp1, Wsp2, spart);
    // head finalize
    finalize_kernel<<<(NNODES / 2 + 255) / 256, 256, 0, stream>>>(
        spart, bsp1, bsp2, Wl, bl, y);
}